// Round 4
// baseline (1045.414 us; speedup 1.0000x reference)
//
#include <hip/hip_runtime.h>
#include <hip/hip_bf16.h>

#define NN 100000
#define NE 1600000
#define IN_DIM 33
#define HID 128
#define NG 128
#define NCLS 10

static __device__ __forceinline__ size_t szmul(int a, int b) {
    return (size_t)a * (size_t)b;
}

// ---------------- init ----------------
__global__ void k_init(int* cnt, int* fill, float* gsum, int n) {
    int i = blockIdx.x * blockDim.x + threadIdx.x;
    if (i < n) { cnt[i] = 0; fill[i] = 0; }
    if (i < NG * HID) gsum[i] = 0.0f;
}

// ---------------- CSR build ----------------
__global__ void k_edge_count(const int* __restrict__ col, int* cnt, int e) {
    int i = blockIdx.x * blockDim.x + threadIdx.x;
    if (i < e) atomicAdd(&cnt[col[i]], 1);
}

#define SCAN_B 1024
__global__ void k_scan1(const int* __restrict__ cnt, int* __restrict__ rowptr,
                        int* __restrict__ bsums, int n) {
    __shared__ int s[SCAN_B];
    int t = threadIdx.x;
    int i = blockIdx.x * SCAN_B + t;
    int v = (i < n) ? cnt[i] : 0;
    s[t] = v;
    __syncthreads();
    for (int o = 1; o < SCAN_B; o <<= 1) {
        int a = (t >= o) ? s[t - o] : 0;
        __syncthreads();
        s[t] += a;
        __syncthreads();
    }
    if (i < n) rowptr[i] = s[t] - v;          // exclusive within block
    if (t == SCAN_B - 1) bsums[blockIdx.x] = s[t];
}

__global__ void k_scan2(int* bsums, int nb) {
    if (threadIdx.x == 0 && blockIdx.x == 0) {
        int run = 0;
        for (int b = 0; b < nb; ++b) { int v = bsums[b]; bsums[b] = run; run += v; }
    }
}

__global__ void k_scan3(int* rowptr, const int* __restrict__ bsums, int n, int etot) {
    int i = blockIdx.x * blockDim.x + threadIdx.x;
    if (i < n) rowptr[i] += bsums[i >> 10];
    else if (i == n) rowptr[n] = etot;
}

// scatter RAW weights, packed (src, w_bits) in one 8B store
__global__ void k_edge_scatter(const int* __restrict__ row, const int* __restrict__ col,
                               const float* __restrict__ w,
                               const int* __restrict__ rowptr, int* fill,
                               int2* __restrict__ csr, int e) {
    int i = blockIdx.x * blockDim.x + threadIdx.x;
    if (i < e) {
        int c = col[i];
        int pos = rowptr[c] + atomicAdd(&fill[c], 1);
        csr[pos] = make_int2(row[i], __float_as_int(w[i]));
    }
}

// deg[i] = 1 (self loop) + sum of raw weights into i; dinv = deg^-1/2
__global__ void k_deg(const int* __restrict__ rowptr, const int2* __restrict__ csr,
                      float* __restrict__ dinv, float* __restrict__ selfn, int n) {
    int i = blockIdx.x * blockDim.x + threadIdx.x;
    if (i >= n) return;
    int beg = rowptr[i], end = rowptr[i + 1];
    float d = 1.0f;
    for (int e = beg; e < end; ++e) d += __int_as_float(csr[e].y);
    float di = (d > 0.0f) ? (1.0f / sqrtf(d)) : 0.0f;
    dinv[i] = di;
    selfn[i] = di * di;
}

// csr_w[e] = dinv[src] * w * dinv[dst]
__global__ void k_norm(const int* __restrict__ rowptr, int2* __restrict__ csr,
                       const float* __restrict__ dinv, int n) {
    int i = blockIdx.x * blockDim.x + threadIdx.x;
    if (i >= n) return;
    float dc = dinv[i];
    int beg = rowptr[i], end = rowptr[i + 1];
    for (int e = beg; e < end; ++e) {
        int2 v = csr[e];
        float nw = dinv[v.x] * __int_as_float(v.y) * dc;
        csr[e] = make_int2(v.x, __float_as_int(nw));
    }
}

// ---------------- feature embedding: h = x @ We + be ----------------
__global__ __launch_bounds__(256) void k_feat0(const float* __restrict__ x,
                                               const float* __restrict__ We,
                                               const float* __restrict__ be,
                                               float* __restrict__ h, int n) {
    __shared__ float sX[2][IN_DIM];
    int node0 = blockIdx.x * 2;
    int tid = threadIdx.x;
    if (tid < 2 * IN_DIM) {
        int r = tid / IN_DIM, c = tid % IN_DIM;
        sX[r][c] = (node0 + r < n) ? x[szmul(node0 + r, IN_DIM) + c] : 0.0f;
    }
    __syncthreads();
    int r = tid >> 7;
    int f = tid & (HID - 1);
    int node = node0 + r;
    if (node < n) {
        float a = be[f];
#pragma unroll
        for (int k = 0; k < IN_DIM; ++k) a += sX[r][k] * We[k * HID + f];
        h[szmul(node, HID) + f] = a;
    }
}

// ---------------- GEMM: C = A @ W  (A: n x 128, W: 128 x 128) ----------------
__global__ __launch_bounds__(256) void k_gemm(const float* __restrict__ A,
                                              const float* __restrict__ W,
                                              float* __restrict__ C, int n) {
    __shared__ float sA[64][HID];   // 32 KiB
    int b0 = blockIdx.x * 64;
    int tid = threadIdx.x;
#pragma unroll
    for (int u = 0; u < 8; ++u) {
        int idx = u * 256 + tid;
        int r = idx >> 5, c4 = idx & 31;
        float4 v = make_float4(0.f, 0.f, 0.f, 0.f);
        if (b0 + r < n)
            v = *reinterpret_cast<const float4*>(A + szmul(b0 + r, HID) + c4 * 4);
        *reinterpret_cast<float4*>(&sA[r][c4 * 4]) = v;
    }
    __syncthreads();
    int ty = tid >> 5, tx = tid & 31;
    float acc0[8], acc1[8], acc2[8], acc3[8];
#pragma unroll
    for (int j = 0; j < 8; ++j) { acc0[j] = 0.f; acc1[j] = 0.f; acc2[j] = 0.f; acc3[j] = 0.f; }
    const float* Wp = W + tx * 4;
#pragma unroll 2
    for (int k = 0; k < HID; ++k) {
        float4 w4 = *reinterpret_cast<const float4*>(Wp + (size_t)k * HID);
#pragma unroll
        for (int j = 0; j < 8; ++j) {
            float a = sA[ty * 8 + j][k];
            acc0[j] += a * w4.x;
            acc1[j] += a * w4.y;
            acc2[j] += a * w4.z;
            acc3[j] += a * w4.w;
        }
    }
#pragma unroll
    for (int j = 0; j < 8; ++j) {
        int r = b0 + ty * 8 + j;
        if (r < n) {
            float4 o = make_float4(acc0[j], acc1[j], acc2[j], acc3[j]);
            *reinterpret_cast<float4*>(&C[szmul(r, HID) + tx * 4]) = o;
        }
    }
}

// ---------------- aggregate: h[i] = relu(b + selfn[i]*t[i] + sum_e w_e * t[src_e]) ----
// one 64-lane wave per node; lane holds 2 features; edges broadcast via shfl
__global__ __launch_bounds__(256) void k_aggregate(const float* __restrict__ t,
                                                   const int* __restrict__ rowptr,
                                                   const int2* __restrict__ csr,
                                                   const float* __restrict__ selfn,
                                                   const float* __restrict__ bias,
                                                   float* __restrict__ hout, int n) {
    int i = (blockIdx.x * 256 + threadIdx.x) >> 6;   // node = global wave id
    if (i >= n) return;
    int lane = threadIdx.x & 63;
    int f0 = lane * 2;
    float2 self = *reinterpret_cast<const float2*>(&t[szmul(i, HID) + f0]);
    float2 b2 = *reinterpret_cast<const float2*>(&bias[f0]);
    float sn = selfn[i];
    float a0 = b2.x + sn * self.x;
    float a1 = b2.y + sn * self.y;
    int beg = rowptr[i], end = rowptr[i + 1];
    for (int base = beg; base < end; base += 64) {
        int m = end - base; if (m > 64) m = 64;
        int2 e = make_int2(0, 0);
        if (lane < m) e = csr[base + lane];
        for (int j = 0; j < m; ++j) {
            int src = __shfl(e.x, j);
            float wj = __int_as_float(__shfl(e.y, j));
            float2 tv = *reinterpret_cast<const float2*>(&t[szmul(src, HID) + f0]);
            a0 += wj * tv.x;
            a1 += wj * tv.y;
        }
    }
    float2 o = make_float2(fmaxf(a0, 0.0f), fmaxf(a1, 0.0f));
    *reinterpret_cast<float2*>(&hout[szmul(i, HID) + f0]) = o;
}

// ---------------- pooling ----------------
// batch is sorted: count via binary search, no atomics
__global__ void k_gcount_bs(const int* __restrict__ batch, int* gcnt, int n) {
    int g = threadIdx.x;
    if (g >= NG) return;
    int lo = 0, hi = n;
    while (lo < hi) { int mid = (lo + hi) >> 1; if (batch[mid] < g) lo = mid + 1; else hi = mid; }
    int start = lo;
    lo = 0; hi = n;
    while (lo < hi) { int mid = (lo + hi) >> 1; if (batch[mid] < g + 1) lo = mid + 1; else hi = mid; }
    gcnt[g] = lo - start;
}

__global__ __launch_bounds__(128) void k_pool(const float* __restrict__ h,
                                              const int* __restrict__ batch,
                                              float* gsum, int n) {
    int f = threadIdx.x;
    int i0 = blockIdx.x * 32;
    int i1 = min(i0 + 32, n);
    if (i0 >= n) return;
    float acc = 0.0f;
    int cur = batch[i0];
    for (int i = i0; i < i1; ++i) {
        int g = batch[i];
        if (g != cur) { atomicAdd(&gsum[cur * HID + f], acc); acc = 0.0f; cur = g; }
        acc += h[szmul(i, HID) + f];
    }
    atomicAdd(&gsum[cur * HID + f], acc);
}

// ---------------- readout MLP ----------------
__global__ __launch_bounds__(128) void k_mlp(const float* __restrict__ gsum,
                                             const int* __restrict__ gcnt,
                                             const float* __restrict__ Wr1, const float* __restrict__ br1,
                                             const float* __restrict__ Wr2, const float* __restrict__ br2,
                                             const float* __restrict__ Wr3,
                                             float* __restrict__ out) {
    int g = blockIdx.x;
    int t = threadIdx.x;
    __shared__ float p[HID];
    __shared__ float r1[64];
    __shared__ float r2[32];
    float c = fmaxf((float)gcnt[g], 1.0f);
    p[t] = gsum[g * HID + t] / c;
    __syncthreads();
    if (t < 64) {
        float a = br1[t];
#pragma unroll 8
        for (int k = 0; k < HID; ++k) a += p[k] * Wr1[k * 64 + t];
        r1[t] = fmaxf(a, 0.0f);
    }
    __syncthreads();
    if (t < 32) {
        float a = br2[t];
#pragma unroll 8
        for (int k = 0; k < 64; ++k) a += r1[k] * Wr2[k * 32 + t];
        r2[t] = fmaxf(a, 0.0f);
    }
    __syncthreads();
    if (t < NCLS) {
        float a = 0.0f;
#pragma unroll
        for (int k = 0; k < 32; ++k) a += r2[k] * Wr3[k * NCLS + t];
        out[g * NCLS + t] = a;
    }
}

extern "C" void kernel_launch(void* const* d_in, const int* in_sizes, int n_in,
                              void* d_out, int out_size, void* d_ws, size_t ws_size,
                              hipStream_t stream) {
    const float* x     = (const float*)d_in[0];
    const int*   ei    = (const int*)d_in[1];
    const float* ew    = (const float*)d_in[2];
    const int*   batch = (const int*)d_in[3];
    const float* We  = (const float*)d_in[4];
    const float* be  = (const float*)d_in[5];
    const float* Wl[4] = { (const float*)d_in[6], (const float*)d_in[8],
                           (const float*)d_in[10], (const float*)d_in[12] };
    const float* bl[4] = { (const float*)d_in[7], (const float*)d_in[9],
                           (const float*)d_in[11], (const float*)d_in[13] };
    const float* Wr1 = (const float*)d_in[14];
    const float* br1 = (const float*)d_in[15];
    const float* Wr2 = (const float*)d_in[16];
    const float* br2 = (const float*)d_in[17];
    const float* Wr3 = (const float*)d_in[18];
    float* out = (float*)d_out;

    const int N = in_sizes[3];      // 100000
    const int E = in_sizes[2];      // 1600000
    const int* row = ei;
    const int* col = ei + E;

    // workspace layout
    char* w = (char*)d_ws;
    size_t off = 0;
    auto alloc = [&](size_t bytes) -> void* {
        void* p = w + off;
        off = (off + bytes + 255) & ~(size_t)255;
        return p;
    };
    float* dinv    = (float*)alloc((size_t)N * 4);
    float* selfn   = (float*)alloc((size_t)N * 4);
    int*   cnt     = (int*)  alloc((size_t)N * 4);
    int*   rowptr  = (int*)  alloc((size_t)(N + 1) * 4);
    int*   fill    = (int*)  alloc((size_t)N * 4);
    int*   bsums   = (int*)  alloc(4096);
    int2*  csr     = (int2*) alloc((size_t)E * 8);
    float* h       = (float*)alloc((size_t)N * HID * 4);
    float* t       = (float*)alloc((size_t)N * HID * 4);
    float* gsum    = (float*)alloc((size_t)NG * HID * 4);
    int*   gcnt    = (int*)  alloc((size_t)NG * 4);
    (void)ws_size;

    auto cdiv = [](int a, int b) { return (a + b - 1) / b; };

    k_init<<<cdiv(N, 256), 256, 0, stream>>>(cnt, fill, gsum, N);
    k_edge_count<<<cdiv(E, 256), 256, 0, stream>>>(col, cnt, E);

    int nb = cdiv(N, SCAN_B);
    k_scan1<<<nb, SCAN_B, 0, stream>>>(cnt, rowptr, bsums, N);
    k_scan2<<<1, 64, 0, stream>>>(bsums, nb);
    k_scan3<<<cdiv(N + 1, 256), 256, 0, stream>>>(rowptr, bsums, N, E);
    k_edge_scatter<<<cdiv(E, 256), 256, 0, stream>>>(row, col, ew, rowptr, fill, csr, E);
    k_deg<<<cdiv(N, 256), 256, 0, stream>>>(rowptr, csr, dinv, selfn, N);
    k_norm<<<cdiv(N, 256), 256, 0, stream>>>(rowptr, csr, dinv, N);

    k_feat0<<<cdiv(N, 2), 256, 0, stream>>>(x, We, be, h, N);

    for (int l = 0; l < 4; ++l) {
        k_gemm<<<cdiv(N, 64), 256, 0, stream>>>(h, Wl[l], t, N);
        k_aggregate<<<cdiv(N, 4), 256, 0, stream>>>(t, rowptr, csr, selfn, bl[l], h, N);
    }

    k_gcount_bs<<<1, 128, 0, stream>>>(batch, gcnt, N);
    k_pool<<<cdiv(N, 32), 128, 0, stream>>>(h, batch, gsum, N);
    k_mlp<<<NG, HID, 0, stream>>>(gsum, gcnt, Wr1, br1, Wr2, br2, Wr3, out);

    (void)out_size; (void)n_in;
}

// Round 5
// 914.634 us; speedup vs baseline: 1.1430x; 1.1430x over previous
//
#include <hip/hip_runtime.h>
#include <hip/hip_bf16.h>

#define NN 100000
#define NE 1600000
#define IN_DIM 33
#define HID 128
#define NG 128
#define NCLS 10

static __device__ __forceinline__ size_t szmul(int a, int b) {
    return (size_t)a * (size_t)b;
}

// ---------------- init ----------------
__global__ void k_init(int* cnt, int* fill, float* gsum, int n) {
    int i = blockIdx.x * blockDim.x + threadIdx.x;
    if (i < n) { cnt[i] = 0; fill[i] = 0; }
    if (i < NG * HID) gsum[i] = 0.0f;
}

// ---------------- CSR build ----------------
__global__ void k_edge_count(const int* __restrict__ col, int* cnt, int e) {
    int i = blockIdx.x * blockDim.x + threadIdx.x;
    if (i < e) atomicAdd(&cnt[col[i]], 1);
}

#define SCAN_B 1024
__global__ void k_scan1(const int* __restrict__ cnt, int* __restrict__ rowptr,
                        int* __restrict__ bsums, int n) {
    __shared__ int s[SCAN_B];
    int t = threadIdx.x;
    int i = blockIdx.x * SCAN_B + t;
    int v = (i < n) ? cnt[i] : 0;
    s[t] = v;
    __syncthreads();
    for (int o = 1; o < SCAN_B; o <<= 1) {
        int a = (t >= o) ? s[t - o] : 0;
        __syncthreads();
        s[t] += a;
        __syncthreads();
    }
    if (i < n) rowptr[i] = s[t] - v;          // exclusive within block
    if (t == SCAN_B - 1) bsums[blockIdx.x] = s[t];
}

__global__ void k_scan2(int* bsums, int nb) {
    if (threadIdx.x == 0 && blockIdx.x == 0) {
        int run = 0;
        for (int b = 0; b < nb; ++b) { int v = bsums[b]; bsums[b] = run; run += v; }
    }
}

__global__ void k_scan3(int* rowptr, const int* __restrict__ bsums, int n, int etot) {
    int i = blockIdx.x * blockDim.x + threadIdx.x;
    if (i < n) rowptr[i] += bsums[i >> 10];
    else if (i == n) rowptr[n] = etot;
}

// scatter RAW weights, packed (src, w_bits) in one 8B store
__global__ void k_edge_scatter(const int* __restrict__ row, const int* __restrict__ col,
                               const float* __restrict__ w,
                               const int* __restrict__ rowptr, int* fill,
                               int2* __restrict__ csr, int e) {
    int i = blockIdx.x * blockDim.x + threadIdx.x;
    if (i < e) {
        int c = col[i];
        int pos = rowptr[c] + atomicAdd(&fill[c], 1);
        csr[pos] = make_int2(row[i], __float_as_int(w[i]));
    }
}

// deg[i] = 1 (self loop) + sum of raw weights into i; dinv = deg^-1/2
__global__ void k_deg(const int* __restrict__ rowptr, const int2* __restrict__ csr,
                      float* __restrict__ dinv, float* __restrict__ selfn, int n) {
    int i = blockIdx.x * blockDim.x + threadIdx.x;
    if (i >= n) return;
    int beg = rowptr[i], end = rowptr[i + 1];
    float d = 1.0f;
    for (int e = beg; e < end; ++e) d += __int_as_float(csr[e].y);
    float di = (d > 0.0f) ? (1.0f / sqrtf(d)) : 0.0f;
    dinv[i] = di;
    selfn[i] = di * di;
}

// csr_w[e] = dinv[src]*w*dinv[dst]; also s[i] = selfn[i] + sum(normalized w) = row-sum of A
__global__ void k_norm(const int* __restrict__ rowptr, int2* __restrict__ csr,
                       const float* __restrict__ dinv, const float* __restrict__ selfn,
                       float* __restrict__ s, int n) {
    int i = blockIdx.x * blockDim.x + threadIdx.x;
    if (i >= n) return;
    float dc = dinv[i];
    float acc = selfn[i];
    int beg = rowptr[i], end = rowptr[i + 1];
    for (int e = beg; e < end; ++e) {
        int2 v = csr[e];
        float nw = dinv[v.x] * __int_as_float(v.y) * dc;
        csr[e] = make_int2(v.x, __float_as_int(nw));
        acc += nw;
    }
    s[i] = acc;
}

// ---------------- fused weights: M = We@W1 [33x128], v = be@W1 [128] ----------------
__global__ void k_combine(const float* __restrict__ We, const float* __restrict__ W1,
                          const float* __restrict__ be,
                          float* __restrict__ M, float* __restrict__ v) {
    int f = threadIdx.x;            // 128
    int k = blockIdx.x;             // 0..33; 33 => bias row
    if (k < IN_DIM) {
        float a = 0.0f;
#pragma unroll 8
        for (int j = 0; j < HID; ++j) a += We[k * HID + j] * W1[j * HID + f];
        M[k * HID + f] = a;
    } else {
        float a = 0.0f;
#pragma unroll 8
        for (int j = 0; j < HID; ++j) a += be[j] * W1[j * HID + f];
        v[f] = a;
    }
}

// ---------------- Y = A @ x  (33-dim aggregate, incl self loop) ----------------
__global__ __launch_bounds__(256) void k_agg_x(const float* __restrict__ x,
                                               const int* __restrict__ rowptr,
                                               const int2* __restrict__ csr,
                                               const float* __restrict__ selfn,
                                               float* __restrict__ Y, int n) {
    int i = (blockIdx.x * 256 + threadIdx.x) >> 6;
    if (i >= n) return;
    int lane = threadIdx.x & 63;
    float a = 0.0f;
    if (lane < IN_DIM) a = selfn[i] * x[szmul(i, IN_DIM) + lane];
    int beg = rowptr[i], end = rowptr[i + 1];
    for (int base = beg; base < end; base += 64) {
        int m = end - base; if (m > 64) m = 64;
        int2 e = make_int2(0, 0);
        if (lane < m) e = csr[base + lane];
#pragma unroll 2
        for (int j = 0; j < m; ++j) {
            int src = __shfl(e.x, j);
            float wj = __int_as_float(__shfl(e.y, j));
            if (lane < IN_DIM) a += wj * x[szmul(src, IN_DIM) + lane];
        }
    }
    if (lane < IN_DIM) Y[szmul(i, IN_DIM) + lane] = a;
}

// ---------------- h = relu(Y@M + s*v + b1)  (N x 33 @ 33 x 128) ----------------
__global__ __launch_bounds__(256) void k_gemm33(const float* __restrict__ Y,
                                                const float* __restrict__ M,
                                                const float* __restrict__ v,
                                                const float* __restrict__ s,
                                                const float* __restrict__ b1,
                                                float* __restrict__ h, int n) {
    __shared__ float sY[32 * IN_DIM];
    __shared__ float ss[32];
    int n0 = blockIdx.x * 32;
    int tid = threadIdx.x;
    int cnt = n - n0; if (cnt > 32) cnt = 32;
    for (int idx = tid; idx < cnt * IN_DIM; idx += 256)
        sY[idx] = Y[szmul(n0, IN_DIM) + idx];
    if (tid < cnt) ss[tid] = s[n0 + tid];
    __syncthreads();
    int f = tid & 127, g = tid >> 7;
    float Mc[IN_DIM];
#pragma unroll
    for (int k = 0; k < IN_DIM; ++k) Mc[k] = M[k * HID + f];
    float vf = v[f], bf = b1[f];
    int ndEnd = g * 16 + 16; if (ndEnd > cnt) ndEnd = cnt;
    for (int nd = g * 16; nd < ndEnd; ++nd) {
        float a = bf + ss[nd] * vf;
#pragma unroll
        for (int k = 0; k < IN_DIM; ++k) a += sY[nd * IN_DIM + k] * Mc[k];
        h[szmul(n0 + nd, HID) + f] = fmaxf(a, 0.0f);
    }
}

// ---------------- GEMM: C = A @ W  (A: n x 128, W: 128 x 128) ----------------
__global__ __launch_bounds__(256) void k_gemm(const float* __restrict__ A,
                                              const float* __restrict__ W,
                                              float* __restrict__ C, int n) {
    __shared__ float sA[64][HID];   // 32 KiB
    int b0 = blockIdx.x * 64;
    int tid = threadIdx.x;
#pragma unroll
    for (int u = 0; u < 8; ++u) {
        int idx = u * 256 + tid;
        int r = idx >> 5, c4 = idx & 31;
        float4 v = make_float4(0.f, 0.f, 0.f, 0.f);
        if (b0 + r < n)
            v = *reinterpret_cast<const float4*>(A + szmul(b0 + r, HID) + c4 * 4);
        *reinterpret_cast<float4*>(&sA[r][c4 * 4]) = v;
    }
    __syncthreads();
    int ty = tid >> 5, tx = tid & 31;
    float acc0[8], acc1[8], acc2[8], acc3[8];
#pragma unroll
    for (int j = 0; j < 8; ++j) { acc0[j] = 0.f; acc1[j] = 0.f; acc2[j] = 0.f; acc3[j] = 0.f; }
    const float* Wp = W + tx * 4;
#pragma unroll 2
    for (int k = 0; k < HID; ++k) {
        float4 w4 = *reinterpret_cast<const float4*>(Wp + (size_t)k * HID);
#pragma unroll
        for (int j = 0; j < 8; ++j) {
            float a = sA[ty * 8 + j][k];
            acc0[j] += a * w4.x;
            acc1[j] += a * w4.y;
            acc2[j] += a * w4.z;
            acc3[j] += a * w4.w;
        }
    }
#pragma unroll
    for (int j = 0; j < 8; ++j) {
        int r = b0 + ty * 8 + j;
        if (r < n) {
            float4 o = make_float4(acc0[j], acc1[j], acc2[j], acc3[j]);
            *reinterpret_cast<float4*>(&C[szmul(r, HID) + tx * 4]) = o;
        }
    }
}

// ---------------- aggregate: h[i] = relu(b + selfn[i]*t[i] + sum_e w_e * t[src_e]) ----
// wave per node; lane = (half, feature-quad): halves process edges j and j+1,
// each lane loads float4 (1 KB per wave load-instruction); xor-combine at end.
__global__ __launch_bounds__(256) void k_aggregate(const float* __restrict__ t,
                                                   const int* __restrict__ rowptr,
                                                   const int2* __restrict__ csr,
                                                   const float* __restrict__ selfn,
                                                   const float* __restrict__ bias,
                                                   float* __restrict__ hout, int n) {
    int i = (blockIdx.x * 256 + threadIdx.x) >> 6;
    if (i >= n) return;
    int lane = threadIdx.x & 63;
    int half = lane >> 5;
    int f0 = (lane & 31) << 2;
    float a0 = 0.f, a1 = 0.f, a2 = 0.f, a3 = 0.f;
    if (half == 0) {
        float4 sf = *reinterpret_cast<const float4*>(&t[szmul(i, HID) + f0]);
        float4 b4 = *reinterpret_cast<const float4*>(&bias[f0]);
        float sn = selfn[i];
        a0 = b4.x + sn * sf.x; a1 = b4.y + sn * sf.y;
        a2 = b4.z + sn * sf.z; a3 = b4.w + sn * sf.w;
    }
    int beg = rowptr[i], end = rowptr[i + 1];
    for (int base = beg; base < end; base += 64) {
        int m = end - base; if (m > 64) m = 64;
        int2 e = make_int2(0, 0);
        if (lane < m) e = csr[base + lane];
#pragma unroll 2
        for (int j = 0; j < m; j += 2) {
            int jj = j + half;                    // lanes 0-31: edge j, 32-63: edge j+1
            int src = __shfl(e.x, jj);            // (0,0) beyond m -> contributes 0
            float wj = __int_as_float(__shfl(e.y, jj));
            float4 tv = *reinterpret_cast<const float4*>(&t[szmul(src, HID) + f0]);
            a0 += wj * tv.x; a1 += wj * tv.y; a2 += wj * tv.z; a3 += wj * tv.w;
        }
    }
    a0 += __shfl_xor(a0, 32); a1 += __shfl_xor(a1, 32);
    a2 += __shfl_xor(a2, 32); a3 += __shfl_xor(a3, 32);
    if (half == 0) {
        float4 o = make_float4(fmaxf(a0, 0.f), fmaxf(a1, 0.f),
                               fmaxf(a2, 0.f), fmaxf(a3, 0.f));
        *reinterpret_cast<float4*>(&hout[szmul(i, HID) + f0]) = o;
    }
}

// ---------------- pooling ----------------
__global__ void k_gcount_bs(const int* __restrict__ batch, int* gcnt, int n) {
    int g = threadIdx.x;
    if (g >= NG) return;
    int lo = 0, hi = n;
    while (lo < hi) { int mid = (lo + hi) >> 1; if (batch[mid] < g) lo = mid + 1; else hi = mid; }
    int start = lo;
    lo = 0; hi = n;
    while (lo < hi) { int mid = (lo + hi) >> 1; if (batch[mid] < g + 1) lo = mid + 1; else hi = mid; }
    gcnt[g] = lo - start;
}

__global__ __launch_bounds__(128) void k_pool(const float* __restrict__ h,
                                              const int* __restrict__ batch,
                                              float* gsum, int n) {
    int f = threadIdx.x;
    int i0 = blockIdx.x * 32;
    int i1 = min(i0 + 32, n);
    if (i0 >= n) return;
    float acc = 0.0f;
    int cur = batch[i0];
    for (int i = i0; i < i1; ++i) {
        int g = batch[i];
        if (g != cur) { atomicAdd(&gsum[cur * HID + f], acc); acc = 0.0f; cur = g; }
        acc += h[szmul(i, HID) + f];
    }
    atomicAdd(&gsum[cur * HID + f], acc);
}

// ---------------- readout MLP ----------------
__global__ __launch_bounds__(128) void k_mlp(const float* __restrict__ gsum,
                                             const int* __restrict__ gcnt,
                                             const float* __restrict__ Wr1, const float* __restrict__ br1,
                                             const float* __restrict__ Wr2, const float* __restrict__ br2,
                                             const float* __restrict__ Wr3,
                                             float* __restrict__ out) {
    int g = blockIdx.x;
    int t = threadIdx.x;
    __shared__ float p[HID];
    __shared__ float r1[64];
    __shared__ float r2[32];
    float c = fmaxf((float)gcnt[g], 1.0f);
    p[t] = gsum[g * HID + t] / c;
    __syncthreads();
    if (t < 64) {
        float a = br1[t];
#pragma unroll 8
        for (int k = 0; k < HID; ++k) a += p[k] * Wr1[k * 64 + t];
        r1[t] = fmaxf(a, 0.0f);
    }
    __syncthreads();
    if (t < 32) {
        float a = br2[t];
#pragma unroll 8
        for (int k = 0; k < 64; ++k) a += r1[k] * Wr2[k * 32 + t];
        r2[t] = fmaxf(a, 0.0f);
    }
    __syncthreads();
    if (t < NCLS) {
        float a = 0.0f;
#pragma unroll
        for (int k = 0; k < 32; ++k) a += r2[k] * Wr3[k * NCLS + t];
        out[g * NCLS + t] = a;
    }
}

extern "C" void kernel_launch(void* const* d_in, const int* in_sizes, int n_in,
                              void* d_out, int out_size, void* d_ws, size_t ws_size,
                              hipStream_t stream) {
    const float* x     = (const float*)d_in[0];
    const int*   ei    = (const int*)d_in[1];
    const float* ew    = (const float*)d_in[2];
    const int*   batch = (const int*)d_in[3];
    const float* We  = (const float*)d_in[4];
    const float* be  = (const float*)d_in[5];
    const float* Wl[4] = { (const float*)d_in[6], (const float*)d_in[8],
                           (const float*)d_in[10], (const float*)d_in[12] };
    const float* bl[4] = { (const float*)d_in[7], (const float*)d_in[9],
                           (const float*)d_in[11], (const float*)d_in[13] };
    const float* Wr1 = (const float*)d_in[14];
    const float* br1 = (const float*)d_in[15];
    const float* Wr2 = (const float*)d_in[16];
    const float* br2 = (const float*)d_in[17];
    const float* Wr3 = (const float*)d_in[18];
    float* out = (float*)d_out;

    const int N = in_sizes[3];      // 100000
    const int E = in_sizes[2];      // 1600000
    const int* row = ei;
    const int* col = ei + E;

    // workspace layout
    char* w = (char*)d_ws;
    size_t off = 0;
    auto alloc = [&](size_t bytes) -> void* {
        void* p = w + off;
        off = (off + bytes + 255) & ~(size_t)255;
        return p;
    };
    float* dinv    = (float*)alloc((size_t)N * 4);
    float* selfn   = (float*)alloc((size_t)N * 4);
    float* srow    = (float*)alloc((size_t)N * 4);       // row-sums of A
    int*   cnt     = (int*)  alloc((size_t)N * 4);
    int*   rowptr  = (int*)  alloc((size_t)(N + 1) * 4);
    int*   fill    = (int*)  alloc((size_t)N * 4);
    int*   bsums   = (int*)  alloc(4096);
    int2*  csr     = (int2*) alloc((size_t)E * 8);
    float* h       = (float*)alloc((size_t)N * HID * 4);
    float* t       = (float*)alloc((size_t)N * HID * 4);
    float* M       = (float*)alloc((size_t)IN_DIM * HID * 4);
    float* vbe     = (float*)alloc((size_t)HID * 4);
    float* gsum    = (float*)alloc((size_t)NG * HID * 4);
    int*   gcnt    = (int*)  alloc((size_t)NG * 4);
    float* Y       = t;   // alias: Y[N][33] consumed before t is first written
    (void)ws_size;

    auto cdiv = [](int a, int b) { return (a + b - 1) / b; };

    k_init<<<cdiv(N, 256), 256, 0, stream>>>(cnt, fill, gsum, N);
    k_edge_count<<<cdiv(E, 256), 256, 0, stream>>>(col, cnt, E);

    int nb = cdiv(N, SCAN_B);
    k_scan1<<<nb, SCAN_B, 0, stream>>>(cnt, rowptr, bsums, N);
    k_scan2<<<1, 64, 0, stream>>>(bsums, nb);
    k_scan3<<<cdiv(N + 1, 256), 256, 0, stream>>>(rowptr, bsums, N, E);
    k_edge_scatter<<<cdiv(E, 256), 256, 0, stream>>>(row, col, ew, rowptr, fill, csr, E);
    k_deg<<<cdiv(N, 256), 256, 0, stream>>>(rowptr, csr, dinv, selfn, N);
    k_norm<<<cdiv(N, 256), 256, 0, stream>>>(rowptr, csr, dinv, selfn, srow, N);

    // layer 1, restructured: h = relu((A x)(We W1) + s*(be W1) + b1)
    k_combine<<<IN_DIM + 1, HID, 0, stream>>>(We, Wl[0], be, M, vbe);
    k_agg_x<<<cdiv(N, 4), 256, 0, stream>>>(x, rowptr, csr, selfn, Y, N);
    k_gemm33<<<cdiv(N, 32), 256, 0, stream>>>(Y, M, vbe, srow, bl[0], h, N);

    // layers 2-4
    for (int l = 1; l < 4; ++l) {
        k_gemm<<<cdiv(N, 64), 256, 0, stream>>>(h, Wl[l], t, N);
        k_aggregate<<<cdiv(N, 4), 256, 0, stream>>>(t, rowptr, csr, selfn, bl[l], h, N);
    }

    k_gcount_bs<<<1, 128, 0, stream>>>(batch, gcnt, N);
    k_pool<<<cdiv(N, 32), 128, 0, stream>>>(h, batch, gsum, N);
    k_mlp<<<NG, HID, 0, stream>>>(gsum, gcnt, Wr1, br1, Wr2, br2, Wr3, out);

    (void)out_size; (void)n_in;
}